// Round 6
// baseline (258.206 us; speedup 1.0000x reference)
//
#include <hip/hip_runtime.h>
#include <math.h>

typedef unsigned int u32;
typedef __attribute__((ext_vector_type(4))) unsigned int uint4v;

// out[r][c] = h[r][c] * S[c][c], S diagonal +-1 (fp32) => XOR of fp32 sign bit.
//
// v7: plain cached loads + NT stores, wave-contiguous. Experiment matrix:
//            strided(16MiB)   contiguous(8KB/wave)
//   NT ld  : R0 <79us         v5/v6 ~67us
//   plain  : R2/R3 95-105us   <-- THIS ROUND (never tested)
// m13 copy ubench (plain loads, contiguous, R+W) = 6.29 TB/s on this chip;
// our NT-contiguous = ~4.0 TB/s effective. Only structural delta left is
// the load hint. h (134MB) fits L3 (256MB) when NT stores keep the dead
// output stream out; FETCH=66MB shows half-residency even with evict-first
// NT loads -> plain loads should pin h fully (FETCH -> ~0), floor becomes
// the NT write drain (~131MB @ 6.5 TB/s ~ 20us).
// R3's plain-load regression is attributed to strided allocation churn.

__global__ __launch_bounds__(256) void parity_mask_kernel(
    const u32* __restrict__ S, u32* __restrict__ mask, int dim)
{
    const int c = blockIdx.x * blockDim.x + threadIdx.x;
    if (c < dim) mask[c] = S[(long long)c * dim + c] & 0x80000000u;
}

// Fast path: requires n_chunks % 2048 == 0 and cpr % 512 == 0.
// Wave w of block b owns chunks [b*2048 + w*512, +512): contiguous 8 KB.
__global__ __launch_bounds__(256) void parity_apply_contig(
    const uint4v* __restrict__ hv,
    const uint4v* __restrict__ maskv,   // cpr sign-mask chunks (16 KB, L2-hit)
    uint4v* __restrict__ ov,
    int cpr)
{
    const int t    = threadIdx.x;
    const int lane = t & 63;
    const int wv   = t >> 6;
    const long long base_w = (long long)blockIdx.x * 2048 + (long long)wv * 512;
    const int mb = (int)(base_w % cpr);

    uint4v m[8], v[8];
#pragma unroll
    for (int k = 0; k < 8; ++k)
        m[k] = maskv[mb + lane + 64 * k];            // coalesced, L2-hit
#pragma unroll
    for (int k = 0; k < 8; ++k)
        v[k] = hv[base_w + lane + 64 * k];           // PLAIN cached load (v7)
#pragma unroll
    for (int k = 0; k < 8; ++k) v[k] ^= m[k];
#pragma unroll
    for (int k = 0; k < 8; ++k)
        __builtin_nontemporal_store(v[k], &ov[base_w + lane + 64 * k]);
}

// Generic path: strided batch-8 fast lane + grid-stride tail (NT, proven R0).
__global__ __launch_bounds__(256) void parity_apply_kernel(
    const uint4v* __restrict__ hv,
    const uint4v* __restrict__ maskv,
    uint4v* __restrict__ ov,
    int cpr,
    long long n_chunks)
{
    const long long tid = (long long)blockIdx.x * blockDim.x + threadIdx.x;
    const long long s   = (long long)gridDim.x * blockDim.x;

    if ((s % cpr) == 0 && tid + 7 * s < n_chunks) {
        const uint4v m = maskv[(int)(tid % cpr)];
        uint4v v[8];
#pragma unroll
        for (int k = 0; k < 8; ++k)
            v[k] = __builtin_nontemporal_load(&hv[tid + k * s]);
#pragma unroll
        for (int k = 0; k < 8; ++k) v[k] ^= m;
#pragma unroll
        for (int k = 0; k < 8; ++k)
            __builtin_nontemporal_store(v[k], &ov[tid + k * s]);
    } else {
        for (long long i = tid; i < n_chunks; i += s) {
            uint4v m = maskv[(int)(i % cpr)];
            uint4v v = __builtin_nontemporal_load(&hv[i]);
            v ^= m;
            __builtin_nontemporal_store(v, &ov[i]);
        }
    }
}

// Fallback (ws too small): read S's diagonal directly.
__global__ __launch_bounds__(256) void parity_fallback_kernel(
    const u32* __restrict__ h, const u32* __restrict__ S, u32* __restrict__ out,
    int dim, long long n_chunks)
{
    const int cpr = dim >> 2;
    const long long tid    = (long long)blockIdx.x * blockDim.x + threadIdx.x;
    const long long stride = (long long)gridDim.x * blockDim.x;
    const uint4v* hv = (const uint4v*)h;
    uint4v* ov = (uint4v*)out;
    for (long long i = tid; i < n_chunks; i += stride) {
        const int c0 = (int)(i % cpr) * 4;
        uint4v v = hv[i];
#pragma unroll
        for (int j = 0; j < 4; ++j) {
            const long long c = c0 + j;
            v[j] ^= (S[c * (long long)dim + c] & 0x80000000u);
        }
        __builtin_nontemporal_store(v, &ov[i]);
    }
}

extern "C" void kernel_launch(void* const* d_in, const int* in_sizes, int n_in,
                              void* d_out, int out_size, void* d_ws, size_t ws_size,
                              hipStream_t stream) {
    (void)n_in; (void)out_size;
    const u32* h = (const u32*)d_in[0];
    const u32* S = (const u32*)d_in[1];
    u32* out = (u32*)d_out;

    const long long s_elems = (long long)in_sizes[1];
    const int dim = (int)llroundl(sqrtl((long double)s_elems));  // 4096
    const long long n = (long long)in_sizes[0];
    const long long n_chunks = n >> 2;        // 4 fp32 per 16B chunk
    const int cpr = dim >> 2;                 // 1024

    const int block = 256;
    if (ws_size >= (size_t)dim * sizeof(u32) && (dim & 3) == 0) {
        u32* mask = (u32*)d_ws;
        parity_mask_kernel<<<(dim + block - 1) / block, block, 0, stream>>>(
            S, mask, dim);

        // Contiguous fast path: 2048 chunks (32 KB) per block.
        // 8192x4096: n_chunks = 8,388,608 -> grid = 4096, cpr = 1024 (%512==0).
        if ((cpr % 512) == 0 && (n_chunks % 2048) == 0 &&
            (n_chunks / 2048) <= 0x7fffffffLL) {
            const long long grid = n_chunks / 2048;
            parity_apply_contig<<<(int)grid, block, 0, stream>>>(
                (const uint4v*)h, (const uint4v*)mask, (uint4v*)out, cpr);
        } else {
            long long grid = (n_chunks + (long long)block * 8 - 1) /
                             ((long long)block * 8);
            if (grid < 1) grid = 1;
            parity_apply_kernel<<<(int)grid, block, 0, stream>>>(
                (const uint4v*)h, (const uint4v*)mask, (uint4v*)out, cpr, n_chunks);
        }
    } else {
        int grid = 2048;
        if ((long long)grid * block > n_chunks) {
            grid = (int)((n_chunks + block - 1) / block);
            if (grid < 1) grid = 1;
        }
        parity_fallback_kernel<<<grid, block, 0, stream>>>(h, S, out, dim, n_chunks);
    }
}

// Round 7
// 247.446 us; speedup vs baseline: 1.0435x; 1.0435x over previous
//
#include <hip/hip_runtime.h>
#include <math.h>

typedef unsigned int u32;
typedef __attribute__((ext_vector_type(4))) unsigned int uint4v;

// out[r][c] = h[r][c] * S[c][c], S diagonal +-1 (fp32) => XOR of fp32 sign bit.
//
// v8: NT loads + PLAIN stores, wave-contiguous. Final cell of the hint
// matrix (apply-kernel us):
//   NT/NT:    strided <79 | contig 67   <- v5 best
//   plain/NT: strided 105 | contig 82-84
//   plain/plain: strided 95
//   NT/plain: THIS ROUND
// Evidence for trying it: (1) FETCH=66MB is hint-INVARIANT (R1/R3/R6) =>
// NT stores' "protect L3" role is nil; (2) the only direct store A/B
// (R2 vs R3) has plain stores 10us FASTER; (3) harness fill sustains
// 6.7 TB/s with cached stores. NT loads keep the cheap miss path (R6
// showed plain loads +15us at identical bytes).

__global__ __launch_bounds__(256) void parity_mask_kernel(
    const u32* __restrict__ S, u32* __restrict__ mask, int dim)
{
    const int c = blockIdx.x * blockDim.x + threadIdx.x;
    if (c < dim) mask[c] = S[(long long)c * dim + c] & 0x80000000u;
}

// Fast path: requires n_chunks % 2048 == 0 and cpr % 512 == 0.
// Wave w of block b owns chunks [b*2048 + w*512, +512): contiguous 8 KB.
__global__ __launch_bounds__(256) void parity_apply_contig(
    const uint4v* __restrict__ hv,
    const uint4v* __restrict__ maskv,   // cpr sign-mask chunks (16 KB, L2-hit)
    uint4v* __restrict__ ov,
    int cpr)
{
    const int t    = threadIdx.x;
    const int lane = t & 63;
    const int wv   = t >> 6;
    const long long base_w = (long long)blockIdx.x * 2048 + (long long)wv * 512;
    const int mb = (int)(base_w % cpr);

    uint4v m[8], v[8];
#pragma unroll
    for (int k = 0; k < 8; ++k)
        m[k] = maskv[mb + lane + 64 * k];            // coalesced, L2-hit
#pragma unroll
    for (int k = 0; k < 8; ++k)
        v[k] = __builtin_nontemporal_load(&hv[base_w + lane + 64 * k]);  // NT
#pragma unroll
    for (int k = 0; k < 8; ++k) v[k] ^= m[k];
#pragma unroll
    for (int k = 0; k < 8; ++k)
        ov[base_w + lane + 64 * k] = v[k];           // PLAIN cached store (v8)
}

// Generic path: strided batch-8 fast lane + grid-stride tail (NT/NT, R0).
__global__ __launch_bounds__(256) void parity_apply_kernel(
    const uint4v* __restrict__ hv,
    const uint4v* __restrict__ maskv,
    uint4v* __restrict__ ov,
    int cpr,
    long long n_chunks)
{
    const long long tid = (long long)blockIdx.x * blockDim.x + threadIdx.x;
    const long long s   = (long long)gridDim.x * blockDim.x;

    if ((s % cpr) == 0 && tid + 7 * s < n_chunks) {
        const uint4v m = maskv[(int)(tid % cpr)];
        uint4v v[8];
#pragma unroll
        for (int k = 0; k < 8; ++k)
            v[k] = __builtin_nontemporal_load(&hv[tid + k * s]);
#pragma unroll
        for (int k = 0; k < 8; ++k) v[k] ^= m;
#pragma unroll
        for (int k = 0; k < 8; ++k)
            __builtin_nontemporal_store(v[k], &ov[tid + k * s]);
    } else {
        for (long long i = tid; i < n_chunks; i += s) {
            uint4v m = maskv[(int)(i % cpr)];
            uint4v v = __builtin_nontemporal_load(&hv[i]);
            v ^= m;
            __builtin_nontemporal_store(v, &ov[i]);
        }
    }
}

// Fallback (ws too small): read S's diagonal directly.
__global__ __launch_bounds__(256) void parity_fallback_kernel(
    const u32* __restrict__ h, const u32* __restrict__ S, u32* __restrict__ out,
    int dim, long long n_chunks)
{
    const int cpr = dim >> 2;
    const long long tid    = (long long)blockIdx.x * blockDim.x + threadIdx.x;
    const long long stride = (long long)gridDim.x * blockDim.x;
    const uint4v* hv = (const uint4v*)h;
    uint4v* ov = (uint4v*)out;
    for (long long i = tid; i < n_chunks; i += stride) {
        const int c0 = (int)(i % cpr) * 4;
        uint4v v = hv[i];
#pragma unroll
        for (int j = 0; j < 4; ++j) {
            const long long c = c0 + j;
            v[j] ^= (S[c * (long long)dim + c] & 0x80000000u);
        }
        __builtin_nontemporal_store(v, &ov[i]);
    }
}

extern "C" void kernel_launch(void* const* d_in, const int* in_sizes, int n_in,
                              void* d_out, int out_size, void* d_ws, size_t ws_size,
                              hipStream_t stream) {
    (void)n_in; (void)out_size;
    const u32* h = (const u32*)d_in[0];
    const u32* S = (const u32*)d_in[1];
    u32* out = (u32*)d_out;

    const long long s_elems = (long long)in_sizes[1];
    const int dim = (int)llroundl(sqrtl((long double)s_elems));  // 4096
    const long long n = (long long)in_sizes[0];
    const long long n_chunks = n >> 2;        // 4 fp32 per 16B chunk
    const int cpr = dim >> 2;                 // 1024

    const int block = 256;
    if (ws_size >= (size_t)dim * sizeof(u32) && (dim & 3) == 0) {
        u32* mask = (u32*)d_ws;
        parity_mask_kernel<<<(dim + block - 1) / block, block, 0, stream>>>(
            S, mask, dim);

        // Contiguous fast path: 2048 chunks (32 KB) per block.
        // 8192x4096: n_chunks = 8,388,608 -> grid = 4096, cpr = 1024 (%512==0).
        if ((cpr % 512) == 0 && (n_chunks % 2048) == 0 &&
            (n_chunks / 2048) <= 0x7fffffffLL) {
            const long long grid = n_chunks / 2048;
            parity_apply_contig<<<(int)grid, block, 0, stream>>>(
                (const uint4v*)h, (const uint4v*)mask, (uint4v*)out, cpr);
        } else {
            long long grid = (n_chunks + (long long)block * 8 - 1) /
                             ((long long)block * 8);
            if (grid < 1) grid = 1;
            parity_apply_kernel<<<(int)grid, block, 0, stream>>>(
                (const uint4v*)h, (const uint4v*)mask, (uint4v*)out, cpr, n_chunks);
        }
    } else {
        int grid = 2048;
        if ((long long)grid * block > n_chunks) {
            grid = (int)((n_chunks + block - 1) / block);
            if (grid < 1) grid = 1;
        }
        parity_fallback_kernel<<<grid, block, 0, stream>>>(h, S, out, dim, n_chunks);
    }
}